// Round 7
// baseline (207.312 us; speedup 1.0000x reference)
//
#include <hip/hip_runtime.h>

#define HH 352
#define WW 1216
#define HW (HH*WW)
#define BB 8
#define CLIPV 5.0f
#define MAXR 32

#define VR 22            // dest rows per band (352 = 16*22)
#define NBAND (HH/VR)    // 16
#define PFD 8            // prefetch depth

// ============ tier-1 vertical: streaming, no LDS, 1 wave/block ============
// Each (dir) wave scans a column band and streams dest-row results (W, Swd)
// directly to its own float2 plane. Register ring (VR<=32) for removals.
__global__ __launch_bounds__(64) void crf_vert_s(
    const float* __restrict__ pred_log, const int* __restrict__ mask,
    const float* __restrict__ variance, const float* __restrict__ depth,
    float2* __restrict__ vq0, float2* __restrict__ vq1)
{
    const int lane = threadIdx.x;
    // decode: xcd owns band pair {2x,2x+1}; dir/wc fastest for XCD locality
    const int id   = blockIdx.x;
    const int xcd  = id & 7;
    const int seq  = id >> 3;              // 0..607
    const int wc   = seq % 19;
    const int r    = seq / 19;             // 0..31
    const int dir  = r & 1;
    const int band = xcd * 2 + ((r >> 1) & 1);
    const int b    = r >> 2;               // 0..7
    const int w    = wc * 64 + lane;

    const float* plog_v = pred_log + ((size_t)b*2 + 1) * HW;
    const int*   m  = mask     + (size_t)b*HW;
    const float* vp = variance + ((size_t)b*4 + (dir ? 3 : 2)) * HW;
    const float* d  = depth    + (size_t)b*HW;

    const int h0 = band * VR;
    const int h1 = h0 + VR;

    int   pm[PFD]; float ppl[PFD], pvv[PFD], pdd[PFD];
    float rq_q[VR], rq_w[VR];

    if (dir == 0) {
        float2* oq = vq0 + (size_t)b*HW;
        const int hs = h0 - MAXR;
        #pragma unroll
        for (int p = 0; p < PFD; ++p) {
            int h = hs + p;
            int hc = min(max(h, 0), HH-1);
            int idx = hc * WW + w;
            pm[p]  = (h >= 0) ? m[idx] : 0;
            ppl[p] = plog_v[idx];
            pvv[p] = vp[idx];
            pdd[p] = d[idx];
        }
        float Q = 0.f, W = 0.f, EA = 1.f;
        int last_inv = hs - 1;
        #pragma unroll
        for (int it = 0; it < VR + MAXR; ++it) {
            const int h = hs + it;
            const int sl = it & (PFD-1);
            int   mi = pm[sl];
            float pl = ppl[sl], vvx = pvv[sl], dd = pdd[sl];
            {   // prefetch h+PFD
                int hp = h + PFD;
                int hc = min(max(hp, 0), HH-1);
                int idx = hc * WW + w;
                pm[sl]  = (hp >= 0 && hp < HH) ? m[idx] : 0;
                ppl[sl] = plog_v[idx];
                pvv[sl] = vp[idx];
                pdd[sl] = d[idx];
            }
            if (it >= MAXR) oq[h * WW + w] = make_float2(W, EA * Q);
            bool  res = (mi == 0);
            float g   = __expf(pl);
            float wt  = __expf(-fminf(vvx, CLIPV));
            float q   = wt * dd * __builtin_amdgcn_rcpf(EA);
            q  = res ? 0.f : q;
            wt = res ? 0.f : wt;
            Q  = res ? 0.f : (Q + q);
            W  = res ? 0.f : (W + wt);
            EA = res ? 1.f : (EA * g);
            last_inv = res ? h : last_inv;
            if (it < VR) { rq_q[it] = q; rq_w[it] = wt; }
            if (it >= MAXR) {
                bool alive = (h - MAXR) > last_inv;
                Q -= alive ? rq_q[it - MAXR] : 0.f;
                W -= alive ? rq_w[it - MAXR] : 0.f;
            }
        }
    } else {
        float2* oq = vq1 + (size_t)b*HW;
        const int hs = h1 - 1 + MAXR;
        #pragma unroll
        for (int p = 0; p < PFD; ++p) {
            int h = hs - p;
            int hc = min(max(h, 0), HH-1);
            int idx = hc * WW + w;
            pm[p]  = (h < HH) ? m[idx] : 0;
            ppl[p] = plog_v[idx];
            pvv[p] = vp[idx];
            pdd[p] = d[idx];
        }
        float Q = 0.f, W = 0.f, ED = 1.f;
        int last_inv = hs + 1;
        #pragma unroll
        for (int it = 0; it < VR + MAXR; ++it) {
            const int h = hs - it;
            const int sl = it & (PFD-1);
            int   mi = pm[sl];
            float pl = ppl[sl], vvx = pvv[sl], dd = pdd[sl];
            {   // prefetch h-PFD
                int hp = h - PFD;
                int hc = min(max(hp, 0), HH-1);
                int idx = hc * WW + w;
                pm[sl]  = (hp >= 0 && hp < HH) ? m[idx] : 0;
                ppl[sl] = plog_v[idx];
                pvv[sl] = vp[idx];
                pdd[sl] = d[idx];
            }
            float g   = __expf(pl);
            float EDh = ED * g;
            if (it >= MAXR) oq[h * WW + w] = make_float2(W, Q * __builtin_amdgcn_rcpf(EDh));
            bool  res = (mi == 0);
            float wt  = __expf(-fminf(vvx, CLIPV));
            float q   = wt * dd * EDh;
            q  = res ? 0.f : q;
            wt = res ? 0.f : wt;
            Q  = res ? 0.f : (Q + q);
            W  = res ? 0.f : (W + wt);
            ED = res ? 1.f : EDh;
            last_inv = res ? h : last_inv;
            if (it < VR) { rq_q[it] = q; rq_w[it] = wt; }
            if (it >= MAXR) {
                bool alive = (h + MAXR) < last_inv;
                Q -= alive ? rq_q[it - MAXR] : 0.f;
                W -= alive ? rq_w[it - MAXR] : 0.f;
            }
        }
    }
}

// ============ tier-2 vertical: validated R6 (LDS-combine) ============
__global__ __launch_bounds__(128, 4) void crf_vert(
    const float* __restrict__ pred_log, const int* __restrict__ mask,
    const float* __restrict__ variance, const float* __restrict__ depth,
    float* __restrict__ vw, float* __restrict__ vwd)
{
    __shared__ float2 obuf[2][VR][64];
    const int lane = threadIdx.x & 63;
    const int dir  = threadIdx.x >> 6;
    const int id   = blockIdx.x;
    const int xcd  = id & 7;
    const int seq  = id >> 3;
    const int wc   = seq % 19;
    const int t2   = seq / 19;
    const int band = xcd * 2 + (t2 & 1);
    const int b    = t2 >> 1;
    const int w    = wc * 64 + lane;

    const float* plog_v = pred_log + ((size_t)b*2 + 1) * HW;
    const int*   m  = mask     + (size_t)b*HW;
    const float* vp = variance + ((size_t)b*4 + (dir ? 3 : 2)) * HW;
    const float* d  = depth    + (size_t)b*HW;
    const int h0 = band * VR;
    const int h1 = h0 + VR;

    int   pm[PFD]; float ppl[PFD], pvv[PFD], pdd[PFD];
    float rq_q[VR], rq_w[VR];

    if (dir == 0) {
        const int hs = h0 - MAXR;
        #pragma unroll
        for (int p = 0; p < PFD; ++p) {
            int h = hs + p;
            int hc = min(max(h, 0), HH-1);
            int idx = hc * WW + w;
            pm[p]  = (h >= 0) ? m[idx] : 0;
            ppl[p] = plog_v[idx]; pvv[p] = vp[idx]; pdd[p] = d[idx];
        }
        float Q = 0.f, W = 0.f, EA = 1.f;
        int last_inv = hs - 1;
        #pragma unroll
        for (int it = 0; it < VR + MAXR; ++it) {
            const int h = hs + it;
            const int sl = it & (PFD-1);
            int   mi = pm[sl];
            float pl = ppl[sl], vvx = pvv[sl], dd = pdd[sl];
            {
                int hp = h + PFD;
                int hc = min(max(hp, 0), HH-1);
                int idx = hc * WW + w;
                pm[sl]  = (hp >= 0 && hp < HH) ? m[idx] : 0;
                ppl[sl] = plog_v[idx]; pvv[sl] = vp[idx]; pdd[sl] = d[idx];
            }
            if (it >= MAXR) obuf[0][it - MAXR][lane] = make_float2(W, EA * Q);
            bool  res = (mi == 0);
            float g   = __expf(pl);
            float wt  = __expf(-fminf(vvx, CLIPV));
            float q   = wt * dd * __builtin_amdgcn_rcpf(EA);
            q  = res ? 0.f : q; wt = res ? 0.f : wt;
            Q  = res ? 0.f : (Q + q); W = res ? 0.f : (W + wt);
            EA = res ? 1.f : (EA * g);
            last_inv = res ? h : last_inv;
            if (it < VR) { rq_q[it] = q; rq_w[it] = wt; }
            if (it >= MAXR) {
                bool alive = (h - MAXR) > last_inv;
                Q -= alive ? rq_q[it - MAXR] : 0.f;
                W -= alive ? rq_w[it - MAXR] : 0.f;
            }
        }
    } else {
        const int hs = h1 - 1 + MAXR;
        #pragma unroll
        for (int p = 0; p < PFD; ++p) {
            int h = hs - p;
            int hc = min(max(h, 0), HH-1);
            int idx = hc * WW + w;
            pm[p]  = (h < HH) ? m[idx] : 0;
            ppl[p] = plog_v[idx]; pvv[p] = vp[idx]; pdd[p] = d[idx];
        }
        float Q = 0.f, W = 0.f, ED = 1.f;
        int last_inv = hs + 1;
        #pragma unroll
        for (int it = 0; it < VR + MAXR; ++it) {
            const int h = hs - it;
            const int sl = it & (PFD-1);
            int   mi = pm[sl];
            float pl = ppl[sl], vvx = pvv[sl], dd = pdd[sl];
            {
                int hp = h - PFD;
                int hc = min(max(hp, 0), HH-1);
                int idx = hc * WW + w;
                pm[sl]  = (hp >= 0 && hp < HH) ? m[idx] : 0;
                ppl[sl] = plog_v[idx]; pvv[sl] = vp[idx]; pdd[sl] = d[idx];
            }
            float g   = __expf(pl);
            float EDh = ED * g;
            if (it >= MAXR) obuf[1][VR - 1 - (it - MAXR)][lane] = make_float2(W, Q * __builtin_amdgcn_rcpf(EDh));
            bool  res = (mi == 0);
            float wt  = __expf(-fminf(vvx, CLIPV));
            float q   = wt * dd * EDh;
            q  = res ? 0.f : q; wt = res ? 0.f : wt;
            Q  = res ? 0.f : (Q + q); W = res ? 0.f : (W + wt);
            ED = res ? 1.f : EDh;
            last_inv = res ? h : last_inv;
            if (it < VR) { rq_q[it] = q; rq_w[it] = wt; }
            if (it >= MAXR) {
                bool alive = (h + MAXR) < last_inv;
                Q -= alive ? rq_q[it - MAXR] : 0.f;
                W -= alive ? rq_w[it - MAXR] : 0.f;
            }
        }
    }
    __syncthreads();
    float* pvw  = vw  + (size_t)b*HW;
    float* pvwd = vwd + (size_t)b*HW;
    const int w0 = wc * 64;
    #pragma unroll
    for (int k = 0; k < VR*64; k += 128) {
        int kk = k + threadIdx.x;
        int rr = kk >> 6, l = kk & 63;
        float2 a = obuf[0][rr][l], c = obuf[1][rr][l];
        int idx = (h0 + rr) * WW + w0 + l;
        pvw [idx] = a.x + c.x;
        pvwd[idx] = a.y + c.y;
    }
}

// ===================== horizontal: chunk-anchored wave-scan =====================
__global__ __launch_bounds__(256) void crf_horiz(
    const float* __restrict__ pred_log, const int* __restrict__ mask,
    const float* __restrict__ variance, const float* __restrict__ depth,
    const float* __restrict__ lam_p,
    const float* __restrict__ vw, const float* __restrict__ vwd,
    const float2* __restrict__ vq0, const float2* __restrict__ vq1,
    const int wsmode,
    float* __restrict__ out)
{
    __shared__ float sG[WW];
    __shared__ float sH[WW];
    __shared__ float sI[WW];
    __shared__ float sJ[WW];
    __shared__ float sEt[19], sEti[19], sTw0[19], sTq0[19];
    __shared__ unsigned long long sBal[19];

    const int tid  = threadIdx.x;
    const int lane = tid & 63;
    const int wv   = tid >> 6;
    const int i    = blockIdx.x;
    const int h    = (i & 7) * 44 + (i >> 3);
    const int b    = blockIdx.y;

    const float* plrow = pred_log + (size_t)b*2*HW + h*WW;
    const int*   mrow  = mask     + (size_t)b*HW   + h*WW;
    const float* v0row = variance + (size_t)b*4*HW + h*WW;
    const float* v1row = v0row + HW;
    const float* drow  = depth    + (size_t)b*HW   + h*WW;
    const float*  vwrow = vw  + (size_t)b*HW + h*WW;
    const float*  vwdrow= vwd + (size_t)b*HW + h*WW;
    const float2* vq0row= vq0 + (size_t)b*HW + h*WW;
    const float2* vq1row= vq1 + (size_t)b*HW + h*WW;
    float*       orow  = out + (size_t)b*HW + h*WW;

    float l_pAx[5], l_xw0[5], l_xq0[5], l_iw1[5], l_iq1[5], l_m[5], l_d[5];

    #pragma unroll
    for (int r = 0; r < 5; ++r) {
        int c = r*4 + wv;
        if (c < 19) {
            int j = c*64 + lane;
            float pl  = plrow[j];
            int   mi  = mrow[j];
            float dj  = drow[j];
            float wt0 = __expf(-fminf(v0row[j], CLIPV));
            float wt1 = __expf(-fminf(v1row[j], CLIPV));
            float ipA = pl;
            #pragma unroll
            for (int dlt = 1; dlt < 64; dlt <<= 1) {
                float u = __shfl_up(ipA, dlt, 64);
                if (lane >= dlt) ipA += u;
            }
            float pAx = ipA - pl;
            float S   = __shfl(ipA, 63, 64);
            float Einv = __expf(-pAx);
            float q0 = wt0 * dj * Einv;
            float q1 = wt1 * dj * Einv;
            float iw0 = wt0, iq0 = q0, iw1 = wt1, iq1 = q1;
            #pragma unroll
            for (int dlt = 1; dlt < 64; dlt <<= 1) {
                float a = __shfl_up(iw0, dlt, 64);
                float e = __shfl_up(iq0, dlt, 64);
                float f = __shfl_up(iw1, dlt, 64);
                float g = __shfl_up(iq1, dlt, 64);
                if (lane >= dlt) { iw0 += a; iq0 += e; iw1 += f; iq1 += g; }
            }
            sG[j] = iw0 - wt0;
            sH[j] = iq0 - q0;
            sI[j] = iw1;
            sJ[j] = iq1;
            unsigned long long bal = __ballot(mi == 0);
            if (lane == 63) {
                sEt[c]  = __expf(S);
                sEti[c] = __expf(-S);
                sTw0[c] = iw0;
                sTq0[c] = iq0;
            }
            if (lane == 0) sBal[c] = bal;
            l_pAx[r] = pAx; l_xw0[r] = iw0 - wt0; l_xq0[r] = iq0 - q0;
            l_iw1[r] = iw1; l_iq1[r] = iq1;
            l_m[r] = (float)mi; l_d[r] = dj;
        }
    }
    __syncthreads();

    const float lam = lam_p[0];

    #pragma unroll
    for (int r = 0; r < 5; ++r) {
        int c = r*4 + wv;
        if (c < 19) {
            const int c0 = c*64;
            const int j  = c0 + lane;
            float E = __expf(l_pAx[r]);
            unsigned long long balOwn = sBal[c];
            unsigned long long mb = balOwn & ((1ull << lane) - 1ull);
            int lm = mb ? (c0 + 63 - __builtin_clzll(mb)) : -1;
            if (c > 0 && lane < 32) {
                unsigned long long mp = sBal[c-1] & ~((1ull << (lane + 32)) - 1ull);
                if (mp) { int lm2 = c0 - 64 + 63 - __builtin_clzll(mp); lm = max(lm, lm2); }
            }
            int a0 = max(j - MAXR, lm + 1);
            float W0, Q0;
            if (a0 >= c0) {
                W0 = l_xw0[r] - sG[a0];
                Q0 = E * (l_xq0[r] - sH[a0]);
            } else {
                W0 = l_xw0[r] + (sTw0[c-1] - sG[a0]);
                Q0 = E * l_xq0[r] + E * sEt[c-1] * (sTq0[c-1] - sH[a0]);
            }
            int nm = 1 << 30;
            if (lane < 63) {
                unsigned long long nb = balOwn >> (lane + 1);
                if (nb) nm = j + 1 + __builtin_ctzll(nb);
            }
            if (c < 18 && lane >= 32) {
                unsigned long long nn = sBal[c+1] & ((1ull << (lane - 31)) - 1ull);
                if (nn) nm = min(nm, c0 + 64 + (int)__builtin_ctzll(nn));
            }
            int b1 = min(j + MAXR, nm - 1);
            b1 = min(b1, WW - 1);
            int endin = min(b1, c0 + 63);
            float W1 = 0.f, Q1 = 0.f;
            if (endin > j) {
                W1 = sI[endin] - l_iw1[r];
                Q1 = E * (sJ[endin] - l_iq1[r]);
            }
            if (b1 > c0 + 63) {
                W1 += sI[b1];
                Q1 += E * sEti[c] * sJ[b1];
            }
            float vtw, vtwd;
            if (wsmode) {
                float2 a = vq0row[j], cc = vq1row[j];
                vtw = a.x + cc.x; vtwd = a.y + cc.y;
            } else {
                vtw = vwrow[j]; vtwd = vwdrow[j];
            }
            float totw  = W0 + W1 + vtw;
            float totwd = Q0 + Q1 + vtwd;
            float lat = (totw > 0.f) ? (totwd / fmaxf(totw, 1e-12f)) : 0.f;
            lat *= l_m[r];
            float dj = l_d[r];
            orow[j] = (lat > 0.f) ? (dj * (1.f - lam) + lat * lam) : dj;
        }
    }
}

// ===================== fallback (validated R2 monolithic) =====================
#define BWF 256
#define PADF 32
#define LWF (BWF + 2*PADF)

__global__ __launch_bounds__(256) void crf_fallback(
    const float* __restrict__ pred_log, const int* __restrict__ mask,
    const float* __restrict__ variance, const float* __restrict__ depth,
    const float* __restrict__ lam_p, float* __restrict__ out)
{
    __shared__ float s_m[LWF], s_wt0[LWF], s_wt1[LWF], s_gh[LWF], s_ghi[LWF], s_d[LWF];
    const int t  = threadIdx.x;
    const int i  = blockIdx.x;
    const int h  = (i & 7) * 44 + (i >> 3);
    const int w0 = blockIdx.y * BWF;
    const int b  = blockIdx.z;
    const float* plog_h = pred_log + (size_t)b * 2 * HW;
    const float* plog_v = plog_h + HW;
    const int*   m      = mask   + (size_t)b * HW;
    const float* v0     = variance + (size_t)b * 4 * HW;
    const float* v1     = v0 + HW;
    const float* v2     = v0 + 2 * HW;
    const float* v3     = v0 + 3 * HW;
    const float* d      = depth + (size_t)b * HW;
    for (int j = t; j < LWF; j += BWF) {
        int gw = w0 - PADF + j;
        float mf=0.f, wt0=0.f, wt1=0.f, gh=1.f, ghi=1.f, dd=0.f;
        if (gw >= 0 && gw < WW) {
            int idx = h * WW + gw;
            mf = (float)m[idx];
            float pl = plog_h[idx];
            gh = __expf(pl); ghi = __expf(-pl);
            wt0 = __expf(-fminf(v0[idx], CLIPV));
            wt1 = __expf(-fminf(v1[idx], CLIPV));
            dd = d[idx];
        }
        s_m[j]=mf; s_wt0[j]=wt0; s_wt1[j]=wt1; s_gh[j]=gh; s_ghi[j]=ghi; s_d[j]=dd;
    }
    __syncthreads();
    const int w = w0 + t;
    if (w >= WW) return;
    const int c = t + PADF;
    float totw = 0.f, totwd = 0.f;
    { float e=1.f, valid=1.f;
      #pragma unroll 8
      for (int k=1;k<=MAXR;++k){int s=c-k; valid*=s_m[s]; e*=s_gh[s];
        float wgt=s_wt0[s]*valid; totw+=wgt; totwd+=wgt*e*s_d[s];} }
    { float e=1.f, valid=1.f;
      #pragma unroll 8
      for (int k=1;k<=MAXR;++k){int s=c+k; e*=s_ghi[s-1]; valid*=s_m[s];
        float wgt=s_wt1[s]*valid; totw+=wgt; totwd+=wgt*e*s_d[s];} }
    { const int kup=min(MAXR,h); float e=1.f, valid=1.f;
      #pragma unroll 4
      for (int k=1;k<=kup;++k){int idx=(h-k)*WW+w; valid*=(float)m[idx];
        e*=__expf(plog_v[idx]); float wgt=__expf(-fminf(v2[idx],CLIPV))*valid;
        totw+=wgt; totwd+=wgt*e*d[idx];} }
    { const int kdn=min(MAXR,HH-1-h); float e=1.f, valid=1.f;
      #pragma unroll 4
      for (int k=1;k<=kdn;++k){int idx=(h+k)*WW+w; e*=__expf(-plog_v[idx-WW]);
        valid*=(float)m[idx]; float wgt=__expf(-fminf(v3[idx],CLIPV))*valid;
        totw+=wgt; totwd+=wgt*e*d[idx];} }
    const int base = h * WW + w;
    float lat = (totw > 0.f) ? (totwd / fmaxf(totw, 1e-12f)) : 0.f;
    lat *= s_m[c];
    float lam = lam_p[0];
    float di  = s_d[c];
    out[(size_t)b * HW + base] = (lat > 0.f) ? (di * (1.f - lam) + lat * lam) : di;
}

extern "C" void kernel_launch(void* const* d_in, const int* in_sizes, int n_in,
                              void* d_out, int out_size, void* d_ws, size_t ws_size,
                              hipStream_t stream) {
    const float* pred_log = (const float*)d_in[0];
    const int*   mask     = (const int*)  d_in[1];
    const float* variance = (const float*)d_in[2];
    const float* depthin  = (const float*)d_in[3];
    const float* lam      = (const float*)d_in[4];
    float* out = (float*)d_out;

    const size_t need4 = 2ull * BB * HW * sizeof(float2);   // 54.8 MB
    const size_t need2 = 2ull * BB * HW * sizeof(float);    // 27.4 MB
    if (ws_size >= need4) {
        float2* vq0 = (float2*)d_ws;
        float2* vq1 = vq0 + (size_t)BB * HW;
        dim3 vgrid(19 * 2 * 2 * 8 * 8, 1, 1);               // 4864 single-wave blocks
        hipLaunchKernelGGL(crf_vert_s, vgrid, dim3(64), 0, stream,
                           pred_log, mask, variance, depthin, vq0, vq1);
        dim3 hgrid(HH, BB);
        hipLaunchKernelGGL(crf_horiz, hgrid, dim3(256), 0, stream,
                           pred_log, mask, variance, depthin, lam,
                           (const float*)nullptr, (const float*)nullptr,
                           vq0, vq1, 1, out);
    } else if (ws_size >= need2) {
        float* vw  = (float*)d_ws;
        float* vwd = vw + (size_t)BB * HW;
        dim3 vgrid(19 * NBAND * BB, 1, 1);
        hipLaunchKernelGGL(crf_vert, vgrid, dim3(128), 0, stream,
                           pred_log, mask, variance, depthin, vw, vwd);
        dim3 hgrid(HH, BB);
        hipLaunchKernelGGL(crf_horiz, hgrid, dim3(256), 0, stream,
                           pred_log, mask, variance, depthin, lam,
                           vw, vwd, (const float2*)nullptr, (const float2*)nullptr, 0, out);
    } else {
        dim3 fgrid(HH, (WW + BWF - 1) / BWF, BB);
        hipLaunchKernelGGL(crf_fallback, fgrid, dim3(BWF), 0, stream,
                           pred_log, mask, variance, depthin, lam, out);
    }
}

// Round 8
// 195.094 us; speedup vs baseline: 1.0626x; 1.0626x over previous
//
#include <hip/hip_runtime.h>
#include <stdint.h>

#define HH 352
#define WW 1216
#define HW (HH*WW)
#define BB 8
#define CLIPV 5.0f
#define MAXR 32

#define VR 22            // dest rows per band (352 = 16*22)
#define NBAND (HH/VR)    // 16
#define PFD 8            // async prefetch depth (iterations)
#define SLOTS 12         // LDS ring slots (PFD mod SLOTS != 0 -> no clobber)
#define TOT (VR + MAXR)  // 54

// async global->LDS: 4 B per lane, lane i lands at lds_base + 4*i
__device__ __forceinline__ void async_ld4(const void* g, void* l) {
    __builtin_amdgcn_global_load_lds(
        reinterpret_cast<const __attribute__((address_space(1))) uint32_t*>(
            reinterpret_cast<uintptr_t>(g)),
        reinterpret_cast<__attribute__((address_space(3))) uint32_t*>(
            reinterpret_cast<uintptr_t>(l)),
        4, 0, 0);
}
// wait until <=28 vmem ops outstanding (exp=7, lgkm=15 unconstrained)
#define WAIT_VM28() __builtin_amdgcn_s_waitcnt(0x4F7C)

// ============ vertical sliding-window scan, async-LDS staged ============
__global__ __launch_bounds__(128) void crf_vert(
    const float* __restrict__ pred_log, const int* __restrict__ mask,
    const float* __restrict__ variance, const float* __restrict__ depth,
    float2* __restrict__ vq)
{
    // ring[dir][slot][arr][lane]: arr 0=m 1=plog 2=var 3=depth
    __shared__ float ring[2][SLOTS][4][64];
    __shared__ float2 obuf0[VR][64];          // dir0 outputs (W, EA*Q)

    const int lane = threadIdx.x & 63;
    const int dir  = threadIdx.x >> 6;        // 0 = pos_h, 1 = neg_h
    const int id   = blockIdx.x;
    const int xcd  = id & 7;
    const int seq  = id >> 3;
    const int wc   = seq % 19;
    const int t2   = seq / 19;
    const int band = xcd * 2 + (t2 & 1);
    const int b    = t2 >> 1;
    const int w    = wc * 64 + lane;

    const float* plog_v = pred_log + ((size_t)b*2 + 1) * HW;
    const int*   m  = mask     + (size_t)b*HW;
    const float* vp = variance + ((size_t)b*4 + (dir ? 3 : 2)) * HW;
    const float* d  = depth    + (size_t)b*HW;

    const int h0 = band * VR;
    const int h1 = h0 + VR;
    const int hs   = dir ? (h1 - 1 + MAXR) : (h0 - MAXR);
    const int step = dir ? -1 : 1;

    float rq_q[VR], rq_w[VR];                 // removal ring (regs, static idx)
    float obw[VR], obq[VR];                   // dir1 output buffer (regs)

    // ---- prologue: issue PFD iterations of async loads ----
    #pragma unroll
    for (int p = 0; p < PFD; ++p) {
        int hp = hs + p * step;
        int hc = min(max(hp, 0), HH-1);
        int idx = hc * WW + w;
        float* base = &ring[dir][p % SLOTS][0][0];
        async_ld4(&m[idx],      base + 0*64 + lane);
        async_ld4(&plog_v[idx], base + 1*64 + lane);
        async_ld4(&vp[idx],     base + 2*64 + lane);
        async_ld4(&d[idx],      base + 3*64 + lane);
    }

    float Q = 0.f, W = 0.f, EG = 1.f;         // EG = EA (dir0) or ED (dir1)
    int last_inv = hs - step;

    #pragma unroll
    for (int it = 0; it < TOT; ++it) {
        const int h  = hs + it * step;
        const int sl = it % SLOTS;

        WAIT_VM28();                          // oldest 4 (this slot) retired
        const float* base = &ring[dir][sl][0][0];
        int   mi  = ((unsigned)h < (unsigned)HH) ? __float_as_int(base[0*64 + lane]) : 0;
        float pl  = base[1*64 + lane];
        float vvx = base[2*64 + lane];
        float dd  = base[3*64 + lane];

        {   // issue loads for it+PFD (dummy past end: clamped rows, unread slots)
            int hp = h + PFD * step;
            int hc = min(max(hp, 0), HH-1);
            int idx = hc * WW + w;
            float* nb = &ring[dir][(it + PFD) % SLOTS][0][0];
            async_ld4(&m[idx],      nb + 0*64 + lane);
            async_ld4(&plog_v[idx], nb + 1*64 + lane);
            async_ld4(&vp[idx],     nb + 2*64 + lane);
            async_ld4(&d[idx],      nb + 3*64 + lane);
        }

        bool  res = (mi == 0);
        float g   = __expf(pl);
        float wt  = __expf(-fminf(vvx, CLIPV));
        float q, outw, outq;
        if (dir == 0) {
            // output dest h first (window excludes src h)
            outw = W; outq = EG * Q;
            q = wt * dd * __builtin_amdgcn_rcpf(EG);
            q  = res ? 0.f : q;
            wt = res ? 0.f : wt;
            Q  = res ? 0.f : (Q + q);
            W  = res ? 0.f : (W + wt);
            EG = res ? 1.f : (EG * g);
        } else {
            float EDh = EG * g;               // exp(D(h)), includes plog(h)
            outw = W; outq = Q * __builtin_amdgcn_rcpf(EDh);
            q = wt * dd * EDh;
            q  = res ? 0.f : q;
            wt = res ? 0.f : wt;
            Q  = res ? 0.f : (Q + q);
            W  = res ? 0.f : (W + wt);
            EG = res ? 1.f : EDh;
        }
        last_inv = res ? h : last_inv;

        if (it >= MAXR) {
            if (dir == 0) obuf0[it - MAXR][lane] = make_float2(outw, outq);
            else { obw[VR - 1 - (it - MAXR)] = outw; obq[VR - 1 - (it - MAXR)] = outq; }
        }
        if (it < VR) { rq_q[it] = q; rq_w[it] = wt; }
        if (it >= MAXR) {
            int s_out = h - MAXR * step;
            bool alive = dir ? (s_out < last_inv) : (s_out > last_inv);
            Q -= alive ? rq_q[it - MAXR] : 0.f;
            W -= alive ? rq_w[it - MAXR] : 0.f;
        }
    }

    __syncthreads();
    // wave1 merges dir0 (LDS) + dir1 (regs), single float2 plane write
    if (dir == 1) {
        float2* pvq = vq + (size_t)b*HW;
        const int w0 = wc * 64;
        #pragma unroll
        for (int r = 0; r < VR; ++r) {
            float2 a = obuf0[r][lane];
            pvq[(h0 + r) * WW + w0 + lane] = make_float2(a.x + obw[r], a.y + obq[r]);
        }
    }
}

// ===================== horizontal: chunk-anchored wave-scan =====================
__global__ __launch_bounds__(256) void crf_horiz(
    const float* __restrict__ pred_log, const int* __restrict__ mask,
    const float* __restrict__ variance, const float* __restrict__ depth,
    const float* __restrict__ lam_p,
    const float2* __restrict__ vq,
    float* __restrict__ out)
{
    __shared__ float sG[WW];
    __shared__ float sH[WW];
    __shared__ float sI[WW];
    __shared__ float sJ[WW];
    __shared__ float sEt[19], sEti[19], sTw0[19], sTq0[19];
    __shared__ unsigned long long sBal[19];

    const int tid  = threadIdx.x;
    const int lane = tid & 63;
    const int wv   = tid >> 6;
    const int i    = blockIdx.x;
    const int h    = (i & 7) * 44 + (i >> 3);
    const int b    = blockIdx.y;

    const float* plrow = pred_log + (size_t)b*2*HW + h*WW;
    const int*   mrow  = mask     + (size_t)b*HW   + h*WW;
    const float* v0row = variance + (size_t)b*4*HW + h*WW;
    const float* v1row = v0row + HW;
    const float* drow  = depth    + (size_t)b*HW   + h*WW;
    const float2* vqrow= vq  + (size_t)b*HW + h*WW;
    float*       orow  = out + (size_t)b*HW + h*WW;

    float l_pAx[5], l_xw0[5], l_xq0[5], l_iw1[5], l_iq1[5], l_m[5], l_d[5];

    #pragma unroll
    for (int r = 0; r < 5; ++r) {
        int c = r*4 + wv;
        if (c < 19) {
            int j = c*64 + lane;
            float pl  = plrow[j];
            int   mi  = mrow[j];
            float dj  = drow[j];
            float wt0 = __expf(-fminf(v0row[j], CLIPV));
            float wt1 = __expf(-fminf(v1row[j], CLIPV));
            float ipA = pl;
            #pragma unroll
            for (int dlt = 1; dlt < 64; dlt <<= 1) {
                float u = __shfl_up(ipA, dlt, 64);
                if (lane >= dlt) ipA += u;
            }
            float pAx = ipA - pl;
            float S   = __shfl(ipA, 63, 64);
            float Einv = __expf(-pAx);
            float q0 = wt0 * dj * Einv;
            float q1 = wt1 * dj * Einv;
            float iw0 = wt0, iq0 = q0, iw1 = wt1, iq1 = q1;
            #pragma unroll
            for (int dlt = 1; dlt < 64; dlt <<= 1) {
                float a = __shfl_up(iw0, dlt, 64);
                float e = __shfl_up(iq0, dlt, 64);
                float f = __shfl_up(iw1, dlt, 64);
                float g = __shfl_up(iq1, dlt, 64);
                if (lane >= dlt) { iw0 += a; iq0 += e; iw1 += f; iq1 += g; }
            }
            sG[j] = iw0 - wt0;
            sH[j] = iq0 - q0;
            sI[j] = iw1;
            sJ[j] = iq1;
            unsigned long long bal = __ballot(mi == 0);
            if (lane == 63) {
                sEt[c]  = __expf(S);
                sEti[c] = __expf(-S);
                sTw0[c] = iw0;
                sTq0[c] = iq0;
            }
            if (lane == 0) sBal[c] = bal;
            l_pAx[r] = pAx; l_xw0[r] = iw0 - wt0; l_xq0[r] = iq0 - q0;
            l_iw1[r] = iw1; l_iq1[r] = iq1;
            l_m[r] = (float)mi; l_d[r] = dj;
        }
    }
    __syncthreads();

    const float lam = lam_p[0];

    #pragma unroll
    for (int r = 0; r < 5; ++r) {
        int c = r*4 + wv;
        if (c < 19) {
            const int c0 = c*64;
            const int j  = c0 + lane;
            float E = __expf(l_pAx[r]);
            unsigned long long balOwn = sBal[c];
            unsigned long long mb = balOwn & ((1ull << lane) - 1ull);
            int lm = mb ? (c0 + 63 - __builtin_clzll(mb)) : -1;
            if (c > 0 && lane < 32) {
                unsigned long long mp = sBal[c-1] & ~((1ull << (lane + 32)) - 1ull);
                if (mp) { int lm2 = c0 - 64 + 63 - __builtin_clzll(mp); lm = max(lm, lm2); }
            }
            int a0 = max(j - MAXR, lm + 1);
            float W0, Q0;
            if (a0 >= c0) {
                W0 = l_xw0[r] - sG[a0];
                Q0 = E * (l_xq0[r] - sH[a0]);
            } else {
                W0 = l_xw0[r] + (sTw0[c-1] - sG[a0]);
                Q0 = E * l_xq0[r] + E * sEt[c-1] * (sTq0[c-1] - sH[a0]);
            }
            int nm = 1 << 30;
            if (lane < 63) {
                unsigned long long nb = balOwn >> (lane + 1);
                if (nb) nm = j + 1 + __builtin_ctzll(nb);
            }
            if (c < 18 && lane >= 32) {
                unsigned long long nn = sBal[c+1] & ((1ull << (lane - 31)) - 1ull);
                if (nn) nm = min(nm, c0 + 64 + (int)__builtin_ctzll(nn));
            }
            int b1 = min(j + MAXR, nm - 1);
            b1 = min(b1, WW - 1);
            int endin = min(b1, c0 + 63);
            float W1 = 0.f, Q1 = 0.f;
            if (endin > j) {
                W1 = sI[endin] - l_iw1[r];
                Q1 = E * (sJ[endin] - l_iq1[r]);
            }
            if (b1 > c0 + 63) {
                W1 += sI[b1];
                Q1 += E * sEti[c] * sJ[b1];
            }
            float2 vt = vqrow[j];
            float totw  = W0 + W1 + vt.x;
            float totwd = Q0 + Q1 + vt.y;
            float lat = (totw > 0.f) ? (totwd / fmaxf(totw, 1e-12f)) : 0.f;
            lat *= l_m[r];
            float dj = l_d[r];
            orow[j] = (lat > 0.f) ? (dj * (1.f - lam) + lat * lam) : dj;
        }
    }
}

// ===================== fallback (validated R2 monolithic) =====================
#define BWF 256
#define PADF 32
#define LWF (BWF + 2*PADF)

__global__ __launch_bounds__(256) void crf_fallback(
    const float* __restrict__ pred_log, const int* __restrict__ mask,
    const float* __restrict__ variance, const float* __restrict__ depth,
    const float* __restrict__ lam_p, float* __restrict__ out)
{
    __shared__ float s_m[LWF], s_wt0[LWF], s_wt1[LWF], s_gh[LWF], s_ghi[LWF], s_d[LWF];
    const int t  = threadIdx.x;
    const int i  = blockIdx.x;
    const int h  = (i & 7) * 44 + (i >> 3);
    const int w0 = blockIdx.y * BWF;
    const int b  = blockIdx.z;
    const float* plog_h = pred_log + (size_t)b * 2 * HW;
    const float* plog_v = plog_h + HW;
    const int*   m      = mask   + (size_t)b * HW;
    const float* v0     = variance + (size_t)b * 4 * HW;
    const float* v1     = v0 + HW;
    const float* v2     = v0 + 2 * HW;
    const float* v3     = v0 + 3 * HW;
    const float* d      = depth + (size_t)b * HW;
    for (int j = t; j < LWF; j += BWF) {
        int gw = w0 - PADF + j;
        float mf=0.f, wt0=0.f, wt1=0.f, gh=1.f, ghi=1.f, dd=0.f;
        if (gw >= 0 && gw < WW) {
            int idx = h * WW + gw;
            mf = (float)m[idx];
            float pl = plog_h[idx];
            gh = __expf(pl); ghi = __expf(-pl);
            wt0 = __expf(-fminf(v0[idx], CLIPV));
            wt1 = __expf(-fminf(v1[idx], CLIPV));
            dd = d[idx];
        }
        s_m[j]=mf; s_wt0[j]=wt0; s_wt1[j]=wt1; s_gh[j]=gh; s_ghi[j]=ghi; s_d[j]=dd;
    }
    __syncthreads();
    const int w = w0 + t;
    if (w >= WW) return;
    const int c = t + PADF;
    float totw = 0.f, totwd = 0.f;
    { float e=1.f, valid=1.f;
      #pragma unroll 8
      for (int k=1;k<=MAXR;++k){int s=c-k; valid*=s_m[s]; e*=s_gh[s];
        float wgt=s_wt0[s]*valid; totw+=wgt; totwd+=wgt*e*s_d[s];} }
    { float e=1.f, valid=1.f;
      #pragma unroll 8
      for (int k=1;k<=MAXR;++k){int s=c+k; e*=s_ghi[s-1]; valid*=s_m[s];
        float wgt=s_wt1[s]*valid; totw+=wgt; totwd+=wgt*e*s_d[s];} }
    { const int kup=min(MAXR,h); float e=1.f, valid=1.f;
      #pragma unroll 4
      for (int k=1;k<=kup;++k){int idx=(h-k)*WW+w; valid*=(float)m[idx];
        e*=__expf(plog_v[idx]); float wgt=__expf(-fminf(v2[idx],CLIPV))*valid;
        totw+=wgt; totwd+=wgt*e*d[idx];} }
    { const int kdn=min(MAXR,HH-1-h); float e=1.f, valid=1.f;
      #pragma unroll 4
      for (int k=1;k<=kdn;++k){int idx=(h+k)*WW+w; e*=__expf(-plog_v[idx-WW]);
        valid*=(float)m[idx]; float wgt=__expf(-fminf(v3[idx],CLIPV))*valid;
        totw+=wgt; totwd+=wgt*e*d[idx];} }
    const int base = h * WW + w;
    float lat = (totw > 0.f) ? (totwd / fmaxf(totw, 1e-12f)) : 0.f;
    lat *= s_m[c];
    float lam = lam_p[0];
    float di  = s_d[c];
    out[(size_t)b * HW + base] = (lat > 0.f) ? (di * (1.f - lam) + lat * lam) : di;
}

extern "C" void kernel_launch(void* const* d_in, const int* in_sizes, int n_in,
                              void* d_out, int out_size, void* d_ws, size_t ws_size,
                              hipStream_t stream) {
    const float* pred_log = (const float*)d_in[0];
    const int*   mask     = (const int*)  d_in[1];
    const float* variance = (const float*)d_in[2];
    const float* depthin  = (const float*)d_in[3];
    const float* lam      = (const float*)d_in[4];
    float* out = (float*)d_out;

    const size_t need = (size_t)BB * HW * sizeof(float2);   // 27.4 MB
    if (ws_size >= need) {
        float2* vq = (float2*)d_ws;
        dim3 vgrid(19 * NBAND * BB, 1, 1);                  // 2432 blocks
        hipLaunchKernelGGL(crf_vert, vgrid, dim3(128), 0, stream,
                           pred_log, mask, variance, depthin, vq);
        dim3 hgrid(HH, BB);
        hipLaunchKernelGGL(crf_horiz, hgrid, dim3(256), 0, stream,
                           pred_log, mask, variance, depthin, lam, vq, out);
    } else {
        dim3 fgrid(HH, (WW + BWF - 1) / BWF, BB);
        hipLaunchKernelGGL(crf_fallback, fgrid, dim3(BWF), 0, stream,
                           pred_log, mask, variance, depthin, lam, out);
    }
}